// Round 8
// baseline (238.372 us; speedup 1.0000x reference)
//
#include <hip/hip_runtime.h>

typedef unsigned short u16;
typedef __attribute__((ext_vector_type(8))) __bf16 bf16x8;
typedef __attribute__((ext_vector_type(8))) u16 u16x8;
typedef __attribute__((ext_vector_type(4))) float f32x4;
typedef __attribute__((ext_vector_type(16))) float f32x16;

__device__ __forceinline__ float bf2f(u16 u){
  union { unsigned int i; float f; } v; v.i = ((unsigned int)u) << 16; return v.f;
}
__device__ __forceinline__ u16 f2bf(float f){
  union { float f; unsigned int u; } v; v.f = f;
  unsigned int u = v.u;
  u += 0x7FFFu + ((u >> 16) & 1u);
  return (u16)(u >> 16);
}
__device__ __forceinline__ unsigned fbits(float f){
  union { float f; unsigned u; } v; v.f = f; return v.u;
}
// async global->LDS, 16B per lane; LDS dest = wave-uniform base + lane*16
__device__ __forceinline__ void gld_lds16(const u16* g, u16* l){
  __builtin_amdgcn_global_load_lds((const __attribute__((address_space(1))) unsigned int*)g,
                                   (__attribute__((address_space(3))) unsigned int*)l, 16, 0, 0);
}

// ---------- prep: weight transposes f32->bf16 + LayerNorm + rk0 zero, one dispatch ----------
// grid (256, 32), block (32,8): bx<96 Wqkv-T ; 96..127 Wo-T ; bx>=128 -> LN row (bx-128)*32+by
__global__ __launch_bounds__(256) void prep_k(const float* __restrict__ Wqkv, u16* __restrict__ wqkvT,
                                              const float* __restrict__ Wo, u16* __restrict__ woT,
                                              float* __restrict__ rk0z,
                                              const float* __restrict__ x, const float* __restrict__ gw,
                                              const float* __restrict__ bw, u16* __restrict__ xnb){
  __shared__ float tile[32][33];
  __shared__ float red[8];
  const int tx = threadIdx.x, ty = threadIdx.y;
  if(blockIdx.x >= 128){
    const int row = (blockIdx.x - 128) * 32 + blockIdx.y;
    const int t = ty * 32 + tx;
    const float* xr = x + (size_t)row * 1024;
    float4 xv = *reinterpret_cast<const float4*>(xr + t * 4);
    float s  = xv.x + xv.y + xv.z + xv.w;
    float s2 = xv.x*xv.x + xv.y*xv.y + xv.z*xv.z + xv.w*xv.w;
    #pragma unroll
    for(int m = 1; m <= 32; m <<= 1){ s += __shfl_xor(s, m, 64); s2 += __shfl_xor(s2, m, 64); }
    const int w = t >> 6, lane = t & 63;
    if(lane == 0){ red[w] = s; red[4 + w] = s2; }
    __syncthreads();
    float S1 = red[0] + red[1] + red[2] + red[3];
    float S2 = red[4] + red[5] + red[6] + red[7];
    float mu = S1 * (1.f/1024.f);
    float var = S2 * (1.f/1024.f) - mu * mu;
    float rstd = rsqrtf(var + 1e-5f);
    float4 gv = *reinterpret_cast<const float4*>(gw + t * 4);
    float4 bv = *reinterpret_cast<const float4*>(bw + t * 4);
    ushort4 o;
    o.x = f2bf((xv.x - mu) * rstd * gv.x + bv.x);
    o.y = f2bf((xv.y - mu) * rstd * gv.y + bv.y);
    o.z = f2bf((xv.z - mu) * rstd * gv.z + bv.z);
    o.w = f2bf((xv.w - mu) * rstd * gv.w + bv.w);
    *reinterpret_cast<ushort4*>(xnb + (size_t)row * 1024 + t * 4) = o;
    return;
  }
  const float* in; u16* out; int C, bxx;
  if(blockIdx.x < 96){ in = Wqkv; out = wqkvT; C = 3072; bxx = blockIdx.x; }
  else               { in = Wo;   out = woT;   C = 1024; bxx = blockIdx.x - 96; }
  if(blockIdx.x == 0 && blockIdx.y == 0){
    float4 z = {0.f, 0.f, 0.f, 0.f};
    reinterpret_cast<float4*>(rk0z)[ty * 32 + tx] = z;
  }
  const int bx = bxx * 32, by = blockIdx.y * 32;
  #pragma unroll
  for(int i = 0; i < 32; i += 8)
    tile[ty + i][tx] = in[(size_t)(by + ty + i) * C + bx + tx];
  __syncthreads();
  #pragma unroll
  for(int i = 0; i < 32; i += 8)
    out[(size_t)(bx + ty + i) * 1024 + by + tx] = f2bf(tile[tx][ty + i]);
}

// ---------- rk0 = r @ Wr : [1024], 32-iter chains, atomics (rk0 zeroed by prep_k) ----------
__global__ __launch_bounds__(256) void rk0_k(const float* __restrict__ r, const float* __restrict__ Wr,
                                             float* __restrict__ rk0){
  const int n = blockIdx.x * 256 + threadIdx.x;
  const int d0 = blockIdx.y * 32;
  float acc = 0.f;
  for(int d = d0; d < d0 + 32; ++d)
    acc += r[d] * Wr[(size_t)d * 1024 + n];
  atomicAdd(&rk0[n], acc);
}

// ---------- c[ib][h] = sum_d (q + rr) * rk0 ; one wave per ib ----------
__global__ __launch_bounds__(256) void c_k(const u16* __restrict__ qk, const float* __restrict__ rr,
                                           const float* __restrict__ rk0, float* __restrict__ cc){
  const int w = threadIdx.x >> 6, lane = threadIdx.x & 63;
  const int ib = blockIdx.x * 4 + w;
  const u16* qp = qk + (size_t)ib * 2048 + lane * 16;
  u16x8 q0 = *reinterpret_cast<const u16x8*>(qp);
  u16x8 q1 = *reinterpret_cast<const u16x8*>(qp + 8);
  const float* rrp = rr + lane * 16;
  const float* rkp = rk0 + lane * 16;
  float s = 0.f;
  #pragma unroll
  for(int e = 0; e < 8; ++e){
    s += (bf2f(q0[e]) + rrp[e]) * rkp[e];
    s += (bf2f(q1[e]) + rrp[8 + e]) * rkp[8 + e];
  }
  s += __shfl_xor(s, 1, 64);
  s += __shfl_xor(s, 2, 64);
  if((lane & 3) == 0) cc[(size_t)ib * 16 + (lane >> 2)] = s;
}

// ---------- V transpose: v_nat[i*2+b][h*64+d] -> vT[(b*16+h)*64+d][i] ----------
__global__ __launch_bounds__(256) void vtrans_k(const u16* __restrict__ vnat, u16* __restrict__ vT){
  __shared__ u16 tl[128][40];
  const int t = threadIdx.x;
  const int i0 = blockIdx.x * 128, c0 = blockIdx.y * 32, b = blockIdx.z;
  {
    const int ii = t & 127, cs = (t >> 7) * 16;
    const u16* p = vnat + (size_t)((i0 + ii) * 2 + b) * 1024 + c0 + cs;
    *reinterpret_cast<u16x8*>(&tl[ii][cs])     = *reinterpret_cast<const u16x8*>(p);
    *reinterpret_cast<u16x8*>(&tl[ii][cs + 8]) = *reinterpret_cast<const u16x8*>(p + 8);
  }
  __syncthreads();
  const int dr = t & 31, seg = t >> 5;
  const int R = (b * 16 + (c0 >> 6)) * 64 + (c0 & 63) + dr;
  u16 tmp[16];
  #pragma unroll
  for(int e = 0; e < 16; ++e) tmp[e] = tl[seg * 16 + e][dr];
  u16* op = vT + (size_t)R * 2048 + i0 + seg * 16;
  *reinterpret_cast<u16x8*>(op)     = *reinterpret_cast<u16x8*>(&tmp[0]);
  *reinterpret_cast<u16x8*>(op + 8) = *reinterpret_cast<u16x8*>(&tmp[8]);
}

// ---------- GEMM1 qkv: BK=64, block-uniform split epilogue ----------
__global__ __launch_bounds__(256) void gemm_qkv_k(const u16* __restrict__ A, const u16* __restrict__ BT,
                                                  u16* __restrict__ Cb, u16* __restrict__ vnat){
  __shared__ u16 sA[2][128 * 32];
  __shared__ u16 sB[2][128 * 32];
  const int t = threadIdx.x;
  const int row0 = blockIdx.y * 128, col0 = blockIdx.x * 128;
  const int w = t >> 6, lane = t & 63, g = lane >> 4, lq = lane & 15;
  const int wr = (w >> 1) * 64, wc = (w & 1) * 64;
  const int K = 1024;
  f32x4 zero4 = {0.f, 0.f, 0.f, 0.f};
  f32x4 acc[4][4];
  #pragma unroll
  for(int mi = 0; mi < 4; ++mi)
    #pragma unroll
    for(int ni = 0; ni < 4; ++ni) acc[mi][ni] = zero4;

  for(int kt = 0; kt < K; kt += 64){
    #pragma unroll
    for(int ks = 0; ks < 2; ++ks){
      const int kk = kt + ks * 32;
      gld_lds16(A  + (size_t)(row0 +      (t >> 2)) * K + kk + (t & 3) * 8, &sA[ks][w * 512]);
      gld_lds16(A  + (size_t)(row0 + 64 + (t >> 2)) * K + kk + (t & 3) * 8, &sA[ks][2048 + w * 512]);
      gld_lds16(BT + (size_t)(col0 +      (t >> 2)) * K + kk + (t & 3) * 8, &sB[ks][w * 512]);
      gld_lds16(BT + (size_t)(col0 + 64 + (t >> 2)) * K + kk + (t & 3) * 8, &sB[ks][2048 + w * 512]);
    }
    __syncthreads();
    #pragma unroll
    for(int ks = 0; ks < 2; ++ks){
      bf16x8 af[4];
      #pragma unroll
      for(int mi = 0; mi < 4; ++mi)
        af[mi] = *reinterpret_cast<const bf16x8*>(&sA[ks][(wr + mi * 16 + lq) * 32 + g * 8]);
      #pragma unroll
      for(int ni = 0; ni < 4; ++ni){
        bf16x8 bfr = *reinterpret_cast<const bf16x8*>(&sB[ks][(wc + ni * 16 + lq) * 32 + g * 8]);
        #pragma unroll
        for(int mi = 0; mi < 4; ++mi)
          acc[mi][ni] = __builtin_amdgcn_mfma_f32_16x16x32_bf16(af[mi], bfr, acc[mi][ni], 0, 0, 0);
      }
    }
    __syncthreads();
  }
  if(blockIdx.x < 16){
    #pragma unroll
    for(int mi = 0; mi < 4; ++mi)
      #pragma unroll
      for(int ni = 0; ni < 4; ++ni)
        #pragma unroll
        for(int rg = 0; rg < 4; ++rg){
          const int row = row0 + wr + mi * 16 + g * 4 + rg;
          const int col = col0 + wc + ni * 16 + lq;
          Cb[(size_t)row * 2048 + col] = f2bf(acc[mi][ni][rg]);
        }
  } else {
    #pragma unroll
    for(int mi = 0; mi < 4; ++mi)
      #pragma unroll
      for(int ni = 0; ni < 4; ++ni)
        #pragma unroll
        for(int rg = 0; rg < 4; ++rg){
          const int row = row0 + wr + mi * 16 + g * 4 + rg;
          const int col = col0 + wc + ni * 16 + lq - 2048;
          vnat[(size_t)row * 1024 + col] = f2bf(acc[mi][ni][rg]);
        }
  }
}

// ---------- GEMM2 out: f32 = av @ woT^T + residual ----------
__global__ __launch_bounds__(256) void gemm_out_k(const u16* __restrict__ A, const u16* __restrict__ BT,
                                                  const u16* __restrict__ res, float* __restrict__ Cf){
  __shared__ u16 sA[128 * 32];
  __shared__ u16 sB[64 * 32];
  const int t = threadIdx.x;
  const int row0 = blockIdx.y * 128, col0 = blockIdx.x * 64;
  const int w = t >> 6, lane = t & 63, g = lane >> 4, lq = lane & 15;
  const int wr = (w >> 1) * 64, wc = (w & 1) * 32;
  const int K = 1024, N = 1024;
  f32x4 zero4 = {0.f, 0.f, 0.f, 0.f};
  f32x4 acc[4][2];
  #pragma unroll
  for(int mi = 0; mi < 4; ++mi)
    #pragma unroll
    for(int ni = 0; ni < 2; ++ni) acc[mi][ni] = zero4;

  for(int kt = 0; kt < K; kt += 32){
    gld_lds16(A  + (size_t)(row0 +      (t >> 2)) * K + kt + (t & 3) * 8, &sA[w * 512]);
    gld_lds16(A  + (size_t)(row0 + 64 + (t >> 2)) * K + kt + (t & 3) * 8, &sA[2048 + w * 512]);
    gld_lds16(BT + (size_t)(col0 +      (t >> 2)) * K + kt + (t & 3) * 8, &sB[w * 512]);
    __syncthreads();
    bf16x8 af[4];
    #pragma unroll
    for(int mi = 0; mi < 4; ++mi)
      af[mi] = *reinterpret_cast<const bf16x8*>(&sA[(wr + mi * 16 + lq) * 32 + g * 8]);
    #pragma unroll
    for(int ni = 0; ni < 2; ++ni){
      bf16x8 bfr = *reinterpret_cast<const bf16x8*>(&sB[(wc + ni * 16 + lq) * 32 + g * 8]);
      #pragma unroll
      for(int mi = 0; mi < 4; ++mi)
        acc[mi][ni] = __builtin_amdgcn_mfma_f32_16x16x32_bf16(af[mi], bfr, acc[mi][ni], 0, 0, 0);
    }
    __syncthreads();
  }
  #pragma unroll
  for(int mi = 0; mi < 4; ++mi)
    #pragma unroll
    for(int ni = 0; ni < 2; ++ni)
      #pragma unroll
      for(int rg = 0; rg < 4; ++rg){
        const int row = row0 + wr + mi * 16 + g * 4 + rg;
        const int col = col0 + wc + ni * 16 + lq;
        Cf[(size_t)row * N + col] = acc[mi][ni][rg] + bf2f(res[(size_t)row * N + col]);
      }
}

// ---------- flash attention core (templated over J-iters; JOFF from blockIdx.z) ----------
// 32x32x16 MFMA, S^T form, shfl-exchange P; writes unnormalized O (bf16) + rsum if SPLIT.
template<int NITER, int SPLIT>
__device__ __forceinline__ void attn_body(const u16* __restrict__ qk, const u16* __restrict__ vT,
                                          const float* __restrict__ rw, const float* __restrict__ cc,
                                          u16* __restrict__ outO, float* __restrict__ prs){
  constexpr int S = 2048, ST = 74;  // 37-dword row stride: 2-way bank aliasing only (free)
  __shared__ u16 ks[2][64 * ST];
  __shared__ u16 vs[2][64 * ST];
  const int t = threadIdx.x;
  const int i0 = blockIdx.x * 128;
  const int bh = blockIdx.y;
  const int b = bh >> 4, h = bh & 15;
  const int z = SPLIT ? blockIdx.z : 0;
  const int jbase = z * (NITER * 64);
  const int w = t >> 6, lane = t & 63, m = lane & 31, q5 = lane >> 5;
  const int iw0 = i0 + w * 32;
  const int i_lane = iw0 + m;
  const float SC = 0.125f * 1.4426950408889634f;

  bf16x8 qf[4];
  {
    const u16* qp = qk + (size_t)(i_lane * 2 + b) * 2048 + h * 64;
    const float* rwp = rw + h * 64;
    #pragma unroll
    for(int kt = 0; kt < 4; ++kt){
      const int dbase = kt * 16 + q5 * 8;
      u16x8 qv = *reinterpret_cast<const u16x8*>(qp + dbase);
      u16x8 a;
      #pragma unroll
      for(int e = 0; e < 8; ++e) a[e] = f2bf((bf2f(qv[e]) + rwp[dbase + e]) * SC);
      qf[kt] = *reinterpret_cast<bf16x8*>(&a);
    }
  }
  const float ciL = cc[(size_t)(i_lane * 2 + b) * 16 + h] * SC;
  const float cpL = (i_lane + 1 < S) ? cc[(size_t)((i_lane + 1) * 2 + b) * 16 + h] * SC : 0.0f;

  f32x16 acc0, acc1, z16;
  #pragma unroll
  for(int e = 0; e < 16; ++e) z16[e] = 0.f;
  acc0 = z16; acc1 = z16;
  float rsum = 0.f;

  const int jr = t >> 2, c0 = (t & 3) * 16;
  {
    const u16* kp = qk + (size_t)((jbase + jr) * 2 + b) * 2048 + 1024 + h * 64 + c0;
    *reinterpret_cast<u16x8*>(&ks[0][jr * ST + c0])     = *reinterpret_cast<const u16x8*>(kp);
    *reinterpret_cast<u16x8*>(&ks[0][jr * ST + c0 + 8]) = *reinterpret_cast<const u16x8*>(kp + 8);
    const u16* vp = vT + ((size_t)bh * 64 + jr) * 2048 + jbase + c0;
    *reinterpret_cast<u16x8*>(&vs[0][jr * ST + c0])     = *reinterpret_cast<const u16x8*>(vp);
    *reinterpret_cast<u16x8*>(&vs[0][jr * ST + c0 + 8]) = *reinterpret_cast<const u16x8*>(vp + 8);
  }
  __syncthreads();

  for(int n = 0; n < NITER; ++n){
    const int p = n & 1;
    u16x8 k0, k1, v0, v1;
    const bool pre = (n + 1 < NITER);
    if(pre){
      const int j0n = jbase + (n + 1) * 64;
      const u16* kp = qk + (size_t)((j0n + jr) * 2 + b) * 2048 + 1024 + h * 64 + c0;
      k0 = *reinterpret_cast<const u16x8*>(kp);
      k1 = *reinterpret_cast<const u16x8*>(kp + 8);
      const u16* vp = vT + ((size_t)bh * 64 + jr) * 2048 + j0n + c0;
      v0 = *reinterpret_cast<const u16x8*>(vp);
      v1 = *reinterpret_cast<const u16x8*>(vp + 8);
    }
    const int j0 = jbase + n * 64;
    bf16x8 pfrag[4];
    #pragma unroll
    for(int jt = 0; jt < 2; ++jt){
      const int tj0 = j0 + jt * 32;
      f32x16 s = z16;
      #pragma unroll
      for(int kt = 0; kt < 4; ++kt){
        bf16x8 ka = *reinterpret_cast<const bf16x8*>(&ks[p][(jt * 32 + m) * ST + kt * 16 + q5 * 8]);
        s = __builtin_amdgcn_mfma_f32_32x32x16_bf16(ka, qf[kt], s, 0, 0, 0);
      }
      float pv[16];
      if(tj0 + 31 <= iw0){
        #pragma unroll
        for(int r = 0; r < 16; ++r) pv[r] = __builtin_amdgcn_exp2f(s[r] + ciL);
      } else if(tj0 >= iw0 + 33){
        #pragma unroll
        for(int r = 0; r < 16; ++r) pv[r] = __builtin_amdgcn_exp2f(s[r] + cpL);
      } else {
        #pragma unroll
        for(int r = 0; r < 16; ++r){
          const int j = tj0 + (r & 3) + 8 * (r >> 2) + 4 * q5;
          const float t1 = (j <= i_lane) ? ciL : cpL;
          const float bdL = (j == i_lane + 1) ? 0.0f : t1;
          pv[r] = __builtin_amdgcn_exp2f(s[r] + bdL);
        }
      }
      #pragma unroll
      for(int r = 0; r < 16; ++r) rsum += pv[r];
      unsigned pk[8];
      #pragma unroll
      for(int q = 0; q < 8; ++q)
        pk[q] = __builtin_amdgcn_perm(fbits(pv[2 * q + 1]), fbits(pv[2 * q]), 0x07060302);
      unsigned sAx = (q5 == 0) ? pk[2] : pk[0];
      unsigned sAy = (q5 == 0) ? pk[3] : pk[1];
      unsigned rAx = (unsigned)__shfl_xor((int)sAx, 32, 64);
      unsigned rAy = (unsigned)__shfl_xor((int)sAy, 32, 64);
      unsigned sBx = (q5 == 0) ? pk[6] : pk[4];
      unsigned sBy = (q5 == 0) ? pk[7] : pk[5];
      unsigned rBx = (unsigned)__shfl_xor((int)sBx, 32, 64);
      unsigned rBy = (unsigned)__shfl_xor((int)sBy, 32, 64);
      union { unsigned u[4]; bf16x8 bf; } f0, f1;
      if(q5 == 0){
        f0.u[0] = pk[0]; f0.u[1] = pk[1]; f0.u[2] = rAx; f0.u[3] = rAy;
        f1.u[0] = pk[4]; f1.u[1] = pk[5]; f1.u[2] = rBx; f1.u[3] = rBy;
      } else {
        f0.u[0] = rAx; f0.u[1] = rAy; f0.u[2] = pk[2]; f0.u[3] = pk[3];
        f1.u[0] = rBx; f1.u[1] = rBy; f1.u[2] = pk[6]; f1.u[3] = pk[7];
      }
      pfrag[jt * 2 + 0] = f0.bf;
      pfrag[jt * 2 + 1] = f1.bf;
    }
    #pragma unroll
    for(int kt = 0; kt < 4; ++kt){
      bf16x8 va0 = *reinterpret_cast<const bf16x8*>(&vs[p][(m) * ST + kt * 16 + q5 * 8]);
      acc0 = __builtin_amdgcn_mfma_f32_32x32x16_bf16(va0, pfrag[kt], acc0, 0, 0, 0);
      bf16x8 va1 = *reinterpret_cast<const bf16x8*>(&vs[p][(32 + m) * ST + kt * 16 + q5 * 8]);
      acc1 = __builtin_amdgcn_mfma_f32_32x32x16_bf16(va1, pfrag[kt], acc1, 0, 0, 0);
    }
    if(pre){
      const int q2 = p ^ 1;
      *reinterpret_cast<u16x8*>(&ks[q2][jr * ST + c0])     = k0;
      *reinterpret_cast<u16x8*>(&ks[q2][jr * ST + c0 + 8]) = k1;
      *reinterpret_cast<u16x8*>(&vs[q2][jr * ST + c0])     = v0;
      *reinterpret_cast<u16x8*>(&vs[q2][jr * ST + c0 + 8]) = v1;
    }
    __syncthreads();
  }
  rsum += __shfl_xor(rsum, 32, 64);
  float rinv = 1.0f;
  if(SPLIT){
    if(q5 == 0) prs[(size_t)z * 65536 + (size_t)(i_lane * 2 + b) * 16 + h] = rsum;
  } else {
    rinv = 1.0f / rsum;
  }
  u16* op = outO + (size_t)(i_lane * 2 + b) * 1024 + h * 64;
  #pragma unroll
  for(int dt = 0; dt < 2; ++dt){
    const f32x16& A = dt ? acc1 : acc0;
    #pragma unroll
    for(int rq = 0; rq < 4; ++rq){
      ushort4 o;
      o.x = f2bf(A[rq * 4 + 0] * rinv);
      o.y = f2bf(A[rq * 4 + 1] * rinv);
      o.z = f2bf(A[rq * 4 + 2] * rinv);
      o.w = f2bf(A[rq * 4 + 3] * rinv);
      const int d0 = dt * 32 + 8 * rq + 4 * q5;
      *reinterpret_cast<ushort4*>(op + d0) = o;
    }
  }
}

// split variant: grid (16,32,2); z=0 writes po0, z=1 writes po1 (=av region)
__global__ __launch_bounds__(256) void attn_split_k(const u16* __restrict__ qk, const u16* __restrict__ vT,
                                                    const float* __restrict__ rw, const float* __restrict__ cc,
                                                    u16* __restrict__ po0, u16* __restrict__ po1,
                                                    float* __restrict__ prs){
  attn_body<16, 1>(qk, vT, rw, cc, (blockIdx.z == 0) ? po0 : po1, prs);
}
// fallback: full j-range, normalized in-kernel
__global__ __launch_bounds__(256) void attn_full_k(const u16* __restrict__ qk, const u16* __restrict__ vT,
                                                   const float* __restrict__ rw, const float* __restrict__ cc,
                                                   u16* __restrict__ av){
  attn_body<32, 0>(qk, vT, rw, cc, av, nullptr);
}

// ---------- combine: av = (po0 + po1) / (r0 + r1) ; one block per row, po1 aliases av ----------
__global__ __launch_bounds__(256) void combine_k(const u16* __restrict__ po0, const u16* __restrict__ po1,
                                                 const float* __restrict__ prs, u16* __restrict__ av){
  const int row = blockIdx.x, t = threadIdx.x;
  const int col = t * 4, h = t >> 4;
  const float r0 = prs[(size_t)row * 16 + h];
  const float r1 = prs[65536 + (size_t)row * 16 + h];
  const float rinv = 1.0f / (r0 + r1);
  ushort4 a = *reinterpret_cast<const ushort4*>(po0 + (size_t)row * 1024 + col);
  ushort4 c = *reinterpret_cast<const ushort4*>(po1 + (size_t)row * 1024 + col);
  ushort4 o;
  o.x = f2bf((bf2f(a.x) + bf2f(c.x)) * rinv);
  o.y = f2bf((bf2f(a.y) + bf2f(c.y)) * rinv);
  o.z = f2bf((bf2f(a.z) + bf2f(c.z)) * rinv);
  o.w = f2bf((bf2f(a.w) + bf2f(c.w)) * rinv);
  *reinterpret_cast<ushort4*>(av + (size_t)row * 1024 + col) = o;
}

extern "C" void kernel_launch(void* const* d_in, const int* in_sizes, int n_in,
                              void* d_out, int out_size, void* d_ws, size_t ws_size,
                              hipStream_t stream){
  (void)in_sizes; (void)n_in; (void)out_size;
  const float* x    = (const float*)d_in[0];
  const float* r    = (const float*)d_in[1];
  const float* rw   = (const float*)d_in[2];
  const float* rr   = (const float*)d_in[3];
  const float* ln_g = (const float*)d_in[4];
  const float* ln_b = (const float*)d_in[5];
  const float* Wqkv = (const float*)d_in[6];
  const float* Wr   = (const float*)d_in[7];
  const float* Wo   = (const float*)d_in[8];
  char* ws = (char*)d_ws;
  u16*   xnb   = (u16*)(ws + 0);                    //  8 MB bf16 [4096,1024]
  u16*   qk    = (u16*)(ws + 8388608);              // 16 MB bf16 [4096,2048] (q | k)
  u16*   av    = (u16*)(ws + 25165824);             //  8 MB bf16 [4096,1024]; = v_nat, = po1
  u16*   woT   = (u16*)(ws + 33554432);             //  2 MB bf16 [1024,1024]
  u16*   wqkvT = (u16*)(ws + 35651584);             //  6 MB bf16 [3072,1024]
  u16*   vT    = (u16*)(ws + 41943040);             //  8 MB bf16 [32,64,2048]
  float* rk0   = (float*)(ws + 50331648);           //  4 KB f32 [1024]
  float* cc    = (float*)(ws + 50335744);           // 256 KB f32 [4096,16]
  float* prs   = (float*)(ws + 50597888);           // 512 KB f32 [2][4096][16]
  u16*   po0   = (u16*)(ws + 51122176);             //  8 MB bf16 [4096,1024] (split partial)
  u16*   vnat  = av;
  float* out   = (float*)d_out;
  const bool split = (ws_size >= 59510784ull);      // po0 end; else fall back to unsplit attn

  prep_k<<<dim3(256, 32), dim3(32, 8), 0, stream>>>(Wqkv, wqkvT, Wo, woT, rk0, x, ln_g, ln_b, xnb);
  rk0_k<<<dim3(4, 32), 256, 0, stream>>>(r, Wr, rk0);
  gemm_qkv_k<<<dim3(24, 32), 256, 0, stream>>>(xnb, wqkvT, qk, vnat);
  vtrans_k<<<dim3(16, 32, 2), 256, 0, stream>>>(vnat, vT);
  c_k<<<1024, 256, 0, stream>>>(qk, rr, rk0, cc);
  if(split){
    attn_split_k<<<dim3(16, 32, 2), 256, 0, stream>>>(qk, vT, rw, cc, po0, av, prs);
    combine_k<<<4096, 256, 0, stream>>>(po0, av, prs, av);
  } else {
    attn_full_k<<<dim3(16, 32), 256, 0, stream>>>(qk, vT, rw, cc, av);
  }
  gemm_out_k<<<dim3(16, 32), 256, 0, stream>>>(av, woT, xnb, out);
}

// Round 9
// 226.143 us; speedup vs baseline: 1.0541x; 1.0541x over previous
//
#include <hip/hip_runtime.h>

typedef unsigned short u16;
typedef __attribute__((ext_vector_type(8))) __bf16 bf16x8;
typedef __attribute__((ext_vector_type(8))) u16 u16x8;
typedef __attribute__((ext_vector_type(4))) float f32x4;
typedef __attribute__((ext_vector_type(16))) float f32x16;

__device__ __forceinline__ float bf2f(u16 u){
  union { unsigned int i; float f; } v; v.i = ((unsigned int)u) << 16; return v.f;
}
__device__ __forceinline__ u16 f2bf(float f){
  union { float f; unsigned int u; } v; v.f = f;
  unsigned int u = v.u;
  u += 0x7FFFu + ((u >> 16) & 1u);
  return (u16)(u >> 16);
}
__device__ __forceinline__ unsigned fbits(float f){
  union { float f; unsigned u; } v; v.f = f; return v.u;
}
// async global->LDS, 16B per lane; LDS dest = wave-uniform base + lane*16
__device__ __forceinline__ void gld_lds16(const u16* g, u16* l){
  __builtin_amdgcn_global_load_lds((const __attribute__((address_space(1))) unsigned int*)g,
                                   (__attribute__((address_space(3))) unsigned int*)l, 16, 0, 0);
}

// ---------- prep: weight transposes + LayerNorm + rk0, one dispatch ----------
// grid (257, 32), block (32,8):
//   bx<96: Wqkv-T ; 96..127: Wo-T ; bx==128: rk0 = r@Wr (n range by*32..+32) ; bx>=129: LN row
__global__ __launch_bounds__(256) void prep_k(const float* __restrict__ Wqkv, u16* __restrict__ wqkvT,
                                              const float* __restrict__ Wo, u16* __restrict__ woT,
                                              const float* __restrict__ r, const float* __restrict__ Wr,
                                              float* __restrict__ rk0,
                                              const float* __restrict__ x, const float* __restrict__ gw,
                                              const float* __restrict__ bw, u16* __restrict__ xnb){
  __shared__ float tile[32][33];
  __shared__ float red[8];
  const int tx = threadIdx.x, ty = threadIdx.y;
  const int t = ty * 32 + tx;
  if(blockIdx.x == 128){
    // rk0[n] = sum_d r[d] * Wr[d*1024+n]
    const int n = blockIdx.y * 32 + (t & 31);
    const int chunk = t >> 5;                 // 8 chunks of 128 d
    float acc = 0.f;
    const int d0 = chunk * 128;
    for(int d = d0; d < d0 + 128; ++d)
      acc += r[d] * Wr[(size_t)d * 1024 + n];
    tile[chunk][t & 31] = acc;
    __syncthreads();
    if(chunk == 0){
      float s = 0.f;
      #pragma unroll
      for(int c = 0; c < 8; ++c) s += tile[c][t & 31];
      rk0[n] = s;
    }
    return;
  }
  if(blockIdx.x >= 129){
    const int row = (blockIdx.x - 129) * 32 + blockIdx.y;
    const float* xr = x + (size_t)row * 1024;
    float4 xv = *reinterpret_cast<const float4*>(xr + t * 4);
    float s  = xv.x + xv.y + xv.z + xv.w;
    float s2 = xv.x*xv.x + xv.y*xv.y + xv.z*xv.z + xv.w*xv.w;
    #pragma unroll
    for(int m = 1; m <= 32; m <<= 1){ s += __shfl_xor(s, m, 64); s2 += __shfl_xor(s2, m, 64); }
    const int w = t >> 6, lane = t & 63;
    if(lane == 0){ red[w] = s; red[4 + w] = s2; }
    __syncthreads();
    float S1 = red[0] + red[1] + red[2] + red[3];
    float S2 = red[4] + red[5] + red[6] + red[7];
    float mu = S1 * (1.f/1024.f);
    float var = S2 * (1.f/1024.f) - mu * mu;
    float rstd = rsqrtf(var + 1e-5f);
    float4 gv = *reinterpret_cast<const float4*>(gw + t * 4);
    float4 bv = *reinterpret_cast<const float4*>(bw + t * 4);
    ushort4 o;
    o.x = f2bf((xv.x - mu) * rstd * gv.x + bv.x);
    o.y = f2bf((xv.y - mu) * rstd * gv.y + bv.y);
    o.z = f2bf((xv.z - mu) * rstd * gv.z + bv.z);
    o.w = f2bf((xv.w - mu) * rstd * gv.w + bv.w);
    *reinterpret_cast<ushort4*>(xnb + (size_t)row * 1024 + t * 4) = o;
    return;
  }
  const float* in; u16* out; int C, bxx;
  if(blockIdx.x < 96){ in = Wqkv; out = wqkvT; C = 3072; bxx = blockIdx.x; }
  else               { in = Wo;   out = woT;   C = 1024; bxx = blockIdx.x - 96; }
  const int bx = bxx * 32, by = blockIdx.y * 32;
  #pragma unroll
  for(int i = 0; i < 32; i += 8)
    tile[ty + i][tx] = in[(size_t)(by + ty + i) * C + bx + tx];
  __syncthreads();
  #pragma unroll
  for(int i = 0; i < 32; i += 8)
    out[(size_t)(bx + ty + i) * 1024 + by + tx] = f2bf(tile[tx][ty + i]);
}

// ---------- GEMM1 qkv: BK=64; epilogue: bx<16 -> qk ; bx>=16 -> vT via LDS transpose ----------
__global__ __launch_bounds__(256) void gemm_qkv_k(const u16* __restrict__ A, const u16* __restrict__ BT,
                                                  u16* __restrict__ Cb, u16* __restrict__ vT){
  __shared__ u16 sA[2][128 * 32];
  __shared__ u16 sB[2][128 * 32];
  __shared__ u16 tl[128 * 66];          // v epilogue transpose tile (64 cols + 2 pad)
  const int t = threadIdx.x;
  const int row0 = blockIdx.y * 128, col0 = blockIdx.x * 128;
  const int w = t >> 6, lane = t & 63, g = lane >> 4, lq = lane & 15;
  const int wr = (w >> 1) * 64, wc = (w & 1) * 64;
  const int K = 1024;
  f32x4 zero4 = {0.f, 0.f, 0.f, 0.f};
  f32x4 acc[4][4];
  #pragma unroll
  for(int mi = 0; mi < 4; ++mi)
    #pragma unroll
    for(int ni = 0; ni < 4; ++ni) acc[mi][ni] = zero4;

  for(int kt = 0; kt < K; kt += 64){
    #pragma unroll
    for(int ks = 0; ks < 2; ++ks){
      const int kk = kt + ks * 32;
      gld_lds16(A  + (size_t)(row0 +      (t >> 2)) * K + kk + (t & 3) * 8, &sA[ks][w * 512]);
      gld_lds16(A  + (size_t)(row0 + 64 + (t >> 2)) * K + kk + (t & 3) * 8, &sA[ks][2048 + w * 512]);
      gld_lds16(BT + (size_t)(col0 +      (t >> 2)) * K + kk + (t & 3) * 8, &sB[ks][w * 512]);
      gld_lds16(BT + (size_t)(col0 + 64 + (t >> 2)) * K + kk + (t & 3) * 8, &sB[ks][2048 + w * 512]);
    }
    __syncthreads();
    #pragma unroll
    for(int ks = 0; ks < 2; ++ks){
      bf16x8 af[4];
      #pragma unroll
      for(int mi = 0; mi < 4; ++mi)
        af[mi] = *reinterpret_cast<const bf16x8*>(&sA[ks][(wr + mi * 16 + lq) * 32 + g * 8]);
      #pragma unroll
      for(int ni = 0; ni < 4; ++ni){
        bf16x8 bfr = *reinterpret_cast<const bf16x8*>(&sB[ks][(wc + ni * 16 + lq) * 32 + g * 8]);
        #pragma unroll
        for(int mi = 0; mi < 4; ++mi)
          acc[mi][ni] = __builtin_amdgcn_mfma_f32_16x16x32_bf16(af[mi], bfr, acc[mi][ni], 0, 0, 0);
      }
    }
    __syncthreads();
  }
  if(blockIdx.x < 16){
    #pragma unroll
    for(int mi = 0; mi < 4; ++mi)
      #pragma unroll
      for(int ni = 0; ni < 4; ++ni)
        #pragma unroll
        for(int rg = 0; rg < 4; ++rg){
          const int row = row0 + wr + mi * 16 + g * 4 + rg;
          const int col = col0 + wc + ni * 16 + lq;
          Cb[(size_t)row * 2048 + col] = f2bf(acc[mi][ni][rg]);
        }
  } else {
    // v: write vT[(b*16+h)*64+d][i] via LDS transpose, two 64-col halves (one head each)
    const int cv0 = col0 - 2048;          // multiple of 128 -> heads cv0/64, cv0/64+1
    #pragma unroll
    for(int half = 0; half < 2; ++half){
      if((w & 1) == half){                // this wave's cols live in this half
        #pragma unroll
        for(int mi = 0; mi < 4; ++mi)
          #pragma unroll
          for(int ni = 0; ni < 4; ++ni)
            #pragma unroll
            for(int rg = 0; rg < 4; ++rg)
              tl[(wr + mi * 16 + g * 4 + rg) * 66 + ni * 16 + lq] = f2bf(acc[mi][ni][rg]);
      }
      __syncthreads();
      const int h = (cv0 >> 6) + half;
      const int b2 = w >> 1, dup = w & 1, d = lane;   // wave-uniform (b2,dup), lane = d
      const int R = (b2 * 16 + h) * 64 + d;
      u16 tmp[32];
      #pragma unroll
      for(int e = 0; e < 32; ++e)
        tmp[e] = tl[((dup * 32 + e) * 2 + b2) * 66 + d];
      u16* op = vT + (size_t)R * 2048 + (row0 >> 1) + dup * 32;
      *reinterpret_cast<u16x8*>(op)      = *reinterpret_cast<u16x8*>(&tmp[0]);
      *reinterpret_cast<u16x8*>(op + 8)  = *reinterpret_cast<u16x8*>(&tmp[8]);
      *reinterpret_cast<u16x8*>(op + 16) = *reinterpret_cast<u16x8*>(&tmp[16]);
      *reinterpret_cast<u16x8*>(op + 24) = *reinterpret_cast<u16x8*>(&tmp[24]);
      __syncthreads();
    }
  }
}

// ---------- GEMM2 out: f32 = av @ woT^T + residual ----------
__global__ __launch_bounds__(256) void gemm_out_k(const u16* __restrict__ A, const u16* __restrict__ BT,
                                                  const u16* __restrict__ res, float* __restrict__ Cf){
  __shared__ u16 sA[128 * 32];
  __shared__ u16 sB[64 * 32];
  const int t = threadIdx.x;
  const int row0 = blockIdx.y * 128, col0 = blockIdx.x * 64;
  const int w = t >> 6, lane = t & 63, g = lane >> 4, lq = lane & 15;
  const int wr = (w >> 1) * 64, wc = (w & 1) * 32;
  const int K = 1024, N = 1024;
  f32x4 zero4 = {0.f, 0.f, 0.f, 0.f};
  f32x4 acc[4][2];
  #pragma unroll
  for(int mi = 0; mi < 4; ++mi)
    #pragma unroll
    for(int ni = 0; ni < 2; ++ni) acc[mi][ni] = zero4;

  for(int kt = 0; kt < K; kt += 32){
    gld_lds16(A  + (size_t)(row0 +      (t >> 2)) * K + kt + (t & 3) * 8, &sA[w * 512]);
    gld_lds16(A  + (size_t)(row0 + 64 + (t >> 2)) * K + kt + (t & 3) * 8, &sA[2048 + w * 512]);
    gld_lds16(BT + (size_t)(col0 +      (t >> 2)) * K + kt + (t & 3) * 8, &sB[w * 512]);
    __syncthreads();
    bf16x8 af[4];
    #pragma unroll
    for(int mi = 0; mi < 4; ++mi)
      af[mi] = *reinterpret_cast<const bf16x8*>(&sA[(wr + mi * 16 + lq) * 32 + g * 8]);
    #pragma unroll
    for(int ni = 0; ni < 2; ++ni){
      bf16x8 bfr = *reinterpret_cast<const bf16x8*>(&sB[(wc + ni * 16 + lq) * 32 + g * 8]);
      #pragma unroll
      for(int mi = 0; mi < 4; ++mi)
        acc[mi][ni] = __builtin_amdgcn_mfma_f32_16x16x32_bf16(af[mi], bfr, acc[mi][ni], 0, 0, 0);
    }
    __syncthreads();
  }
  #pragma unroll
  for(int mi = 0; mi < 4; ++mi)
    #pragma unroll
    for(int ni = 0; ni < 2; ++ni)
      #pragma unroll
      for(int rg = 0; rg < 4; ++rg){
        const int row = row0 + wr + mi * 16 + g * 4 + rg;
        const int col = col0 + wc + ni * 16 + lq;
        Cf[(size_t)row * N + col] = acc[mi][ni][rg] + bf2f(res[(size_t)row * N + col]);
      }
}

// ---------- flash attention: 32x32x16, S^T form, shfl-exchange P, inline BD dot ----------
// grid: (S/128, B*H); block 256 = 4 waves; wave w owns 32 q-rows [i0+32w, i0+32w+32)
__global__ __launch_bounds__(256) void attn_k(const u16* __restrict__ qk, const u16* __restrict__ vT,
                                              const float* __restrict__ rw, const float* __restrict__ rr,
                                              const float* __restrict__ rk0, u16* __restrict__ av){
  constexpr int S = 2048, ST = 74;  // 37-dword row stride: 2-way bank aliasing only (free)
  __shared__ u16 ks[2][64 * ST];
  __shared__ u16 vs[2][64 * ST];
  const int t = threadIdx.x;
  const int i0 = blockIdx.x * 128;
  const int bh = blockIdx.y;
  const int b = bh >> 4, h = bh & 15;
  const int w = t >> 6, lane = t & 63, m = lane & 31, q5 = lane >> 5;
  const int iw0 = i0 + w * 32;
  const int i_lane = iw0 + m;
  const float SC = 0.125f * 1.4426950408889634f;

  // Q B-frags + inline BD dots: ci = sum_d (q[i]+rr)*rk0, cp = same for row i+1
  bf16x8 qf[4];
  float ciL, cpL;
  {
    const bool hasnext = (i_lane + 1 < S);
    const u16* qp  = qk + (size_t)(i_lane * 2 + b) * 2048 + h * 64;
    const u16* qp2 = qk + (size_t)((hasnext ? i_lane + 1 : i_lane) * 2 + b) * 2048 + h * 64;
    const float* rwp = rw  + h * 64;
    const float* rrp = rr  + h * 64;
    const float* rkp = rk0 + h * 64;
    float cpart = 0.f, cppart = 0.f;
    #pragma unroll
    for(int kt = 0; kt < 4; ++kt){
      const int dbase = kt * 16 + q5 * 8;
      u16x8 qv  = *reinterpret_cast<const u16x8*>(qp  + dbase);
      u16x8 qv2 = *reinterpret_cast<const u16x8*>(qp2 + dbase);
      u16x8 a;
      #pragma unroll
      for(int e = 0; e < 8; ++e){
        const float qe  = bf2f(qv[e]);
        const float rke = rkp[dbase + e];
        const float rre = rrp[dbase + e];
        a[e] = f2bf((qe + rwp[dbase + e]) * SC);
        cpart  += (qe + rre) * rke;
        cppart += (bf2f(qv2[e]) + rre) * rke;
      }
      qf[kt] = *reinterpret_cast<bf16x8*>(&a);
    }
    cpart  += __shfl_xor(cpart, 32, 64);   // partner lane holds the other 32 d
    cppart += __shfl_xor(cppart, 32, 64);
    ciL = cpart * SC;
    cpL = hasnext ? cppart * SC : 0.0f;
  }

  f32x16 acc0, acc1, z16;
  #pragma unroll
  for(int e = 0; e < 16; ++e) z16[e] = 0.f;
  acc0 = z16; acc1 = z16;
  float rsum = 0.f;

  const int jr = t >> 2, c0 = (t & 3) * 16;
  {
    const u16* kp = qk + (size_t)(jr * 2 + b) * 2048 + 1024 + h * 64 + c0;
    *reinterpret_cast<u16x8*>(&ks[0][jr * ST + c0])     = *reinterpret_cast<const u16x8*>(kp);
    *reinterpret_cast<u16x8*>(&ks[0][jr * ST + c0 + 8]) = *reinterpret_cast<const u16x8*>(kp + 8);
    const u16* vp = vT + ((size_t)bh * 64 + jr) * 2048 + c0;
    *reinterpret_cast<u16x8*>(&vs[0][jr * ST + c0])     = *reinterpret_cast<const u16x8*>(vp);
    *reinterpret_cast<u16x8*>(&vs[0][jr * ST + c0 + 8]) = *reinterpret_cast<const u16x8*>(vp + 8);
  }
  __syncthreads();

  for(int n = 0; n < 32; ++n){
    const int p = n & 1;
    u16x8 k0, k1, v0, v1;
    const bool pre = (n + 1 < 32);
    if(pre){
      const int j0n = (n + 1) * 64;
      const u16* kp = qk + (size_t)((j0n + jr) * 2 + b) * 2048 + 1024 + h * 64 + c0;
      k0 = *reinterpret_cast<const u16x8*>(kp);
      k1 = *reinterpret_cast<const u16x8*>(kp + 8);
      const u16* vp = vT + ((size_t)bh * 64 + jr) * 2048 + j0n + c0;
      v0 = *reinterpret_cast<const u16x8*>(vp);
      v1 = *reinterpret_cast<const u16x8*>(vp + 8);
    }
    const int j0 = n * 64;
    bf16x8 pfrag[4];
    #pragma unroll
    for(int jt = 0; jt < 2; ++jt){
      const int tj0 = j0 + jt * 32;
      f32x16 s = z16;
      #pragma unroll
      for(int kt = 0; kt < 4; ++kt){
        bf16x8 ka = *reinterpret_cast<const bf16x8*>(&ks[p][(jt * 32 + m) * ST + kt * 16 + q5 * 8]);
        s = __builtin_amdgcn_mfma_f32_32x32x16_bf16(ka, qf[kt], s, 0, 0, 0);
      }
      float pv[16];
      if(tj0 + 31 <= iw0){
        #pragma unroll
        for(int r2 = 0; r2 < 16; ++r2) pv[r2] = __builtin_amdgcn_exp2f(s[r2] + ciL);
      } else if(tj0 >= iw0 + 33){
        #pragma unroll
        for(int r2 = 0; r2 < 16; ++r2) pv[r2] = __builtin_amdgcn_exp2f(s[r2] + cpL);
      } else {
        #pragma unroll
        for(int r2 = 0; r2 < 16; ++r2){
          const int j = tj0 + (r2 & 3) + 8 * (r2 >> 2) + 4 * q5;
          const float t1 = (j <= i_lane) ? ciL : cpL;
          const float bdL = (j == i_lane + 1) ? 0.0f : t1;
          pv[r2] = __builtin_amdgcn_exp2f(s[r2] + bdL);
        }
      }
      #pragma unroll
      for(int r2 = 0; r2 < 16; ++r2) rsum += pv[r2];
      unsigned pk[8];
      #pragma unroll
      for(int q = 0; q < 8; ++q)
        pk[q] = __builtin_amdgcn_perm(fbits(pv[2 * q + 1]), fbits(pv[2 * q]), 0x07060302);
      unsigned sAx = (q5 == 0) ? pk[2] : pk[0];
      unsigned sAy = (q5 == 0) ? pk[3] : pk[1];
      unsigned rAx = (unsigned)__shfl_xor((int)sAx, 32, 64);
      unsigned rAy = (unsigned)__shfl_xor((int)sAy, 32, 64);
      unsigned sBx = (q5 == 0) ? pk[6] : pk[4];
      unsigned sBy = (q5 == 0) ? pk[7] : pk[5];
      unsigned rBx = (unsigned)__shfl_xor((int)sBx, 32, 64);
      unsigned rBy = (unsigned)__shfl_xor((int)sBy, 32, 64);
      union { unsigned u[4]; bf16x8 bf; } f0, f1;
      if(q5 == 0){
        f0.u[0] = pk[0]; f0.u[1] = pk[1]; f0.u[2] = rAx; f0.u[3] = rAy;
        f1.u[0] = pk[4]; f1.u[1] = pk[5]; f1.u[2] = rBx; f1.u[3] = rBy;
      } else {
        f0.u[0] = rAx; f0.u[1] = rAy; f0.u[2] = pk[2]; f0.u[3] = pk[3];
        f1.u[0] = rBx; f1.u[1] = rBy; f1.u[2] = pk[6]; f1.u[3] = pk[7];
      }
      pfrag[jt * 2 + 0] = f0.bf;
      pfrag[jt * 2 + 1] = f1.bf;
    }
    #pragma unroll
    for(int kt = 0; kt < 4; ++kt){
      bf16x8 va0 = *reinterpret_cast<const bf16x8*>(&vs[p][(m) * ST + kt * 16 + q5 * 8]);
      acc0 = __builtin_amdgcn_mfma_f32_32x32x16_bf16(va0, pfrag[kt], acc0, 0, 0, 0);
      bf16x8 va1 = *reinterpret_cast<const bf16x8*>(&vs[p][(32 + m) * ST + kt * 16 + q5 * 8]);
      acc1 = __builtin_amdgcn_mfma_f32_32x32x16_bf16(va1, pfrag[kt], acc1, 0, 0, 0);
    }
    if(pre){
      const int q2 = p ^ 1;
      *reinterpret_cast<u16x8*>(&ks[q2][jr * ST + c0])     = k0;
      *reinterpret_cast<u16x8*>(&ks[q2][jr * ST + c0 + 8]) = k1;
      *reinterpret_cast<u16x8*>(&vs[q2][jr * ST + c0])     = v0;
      *reinterpret_cast<u16x8*>(&vs[q2][jr * ST + c0 + 8]) = v1;
    }
    __syncthreads();
  }
  rsum += __shfl_xor(rsum, 32, 64);
  const float rinv = 1.0f / rsum;
  u16* op = av + (size_t)(i_lane * 2 + b) * 1024 + h * 64;
  #pragma unroll
  for(int dt = 0; dt < 2; ++dt){
    const f32x16& A = dt ? acc1 : acc0;
    #pragma unroll
    for(int rq = 0; rq < 4; ++rq){
      ushort4 o;
      o.x = f2bf(A[rq * 4 + 0] * rinv);
      o.y = f2bf(A[rq * 4 + 1] * rinv);
      o.z = f2bf(A[rq * 4 + 2] * rinv);
      o.w = f2bf(A[rq * 4 + 3] * rinv);
      const int d0 = dt * 32 + 8 * rq + 4 * q5;
      *reinterpret_cast<ushort4*>(op + d0) = o;
    }
  }
}

extern "C" void kernel_launch(void* const* d_in, const int* in_sizes, int n_in,
                              void* d_out, int out_size, void* d_ws, size_t ws_size,
                              hipStream_t stream){
  (void)in_sizes; (void)n_in; (void)out_size; (void)ws_size;
  const float* x    = (const float*)d_in[0];
  const float* r    = (const float*)d_in[1];
  const float* rw   = (const float*)d_in[2];
  const float* rr   = (const float*)d_in[3];
  const float* ln_g = (const float*)d_in[4];
  const float* ln_b = (const float*)d_in[5];
  const float* Wqkv = (const float*)d_in[6];
  const float* Wr   = (const float*)d_in[7];
  const float* Wo   = (const float*)d_in[8];
  char* ws = (char*)d_ws;
  u16*   xnb   = (u16*)(ws + 0);                    //  8 MB bf16 [4096,1024]
  u16*   qk    = (u16*)(ws + 8388608);              // 16 MB bf16 [4096,2048] (q | k)
  u16*   av    = (u16*)(ws + 25165824);             //  8 MB bf16 [4096,1024]
  u16*   woT   = (u16*)(ws + 33554432);             //  2 MB bf16 [1024,1024]
  u16*   wqkvT = (u16*)(ws + 35651584);             //  6 MB bf16 [3072,1024]
  u16*   vT    = (u16*)(ws + 41943040);             //  8 MB bf16 [32,64,2048]
  float* rk0   = (float*)(ws + 50331648);           //  4 KB f32 [1024]
  float* out   = (float*)d_out;

  prep_k<<<dim3(257, 32), dim3(32, 8), 0, stream>>>(Wqkv, wqkvT, Wo, woT, r, Wr, rk0,
                                                    x, ln_g, ln_b, xnb);
  gemm_qkv_k<<<dim3(24, 32), 256, 0, stream>>>(xnb, wqkvT, qk, vT);
  attn_k<<<dim3(16, 32), 256, 0, stream>>>(qk, vT, rw, rr, rk0, av);
  gemm_out_k<<<dim3(16, 32), 256, 0, stream>>>(av, woT, xnb, out);
}